// Round 7
// baseline (103.173 us; speedup 1.0000x reference)
//
#include <hip/hip_runtime.h>
#include <hip/hip_bf16.h>

#define BB 8
#define NN 2048
#define DD 128
#define HP 132    // padded row stride for 128-wide LDS tiles
#define CH 32     // chunk length
#define NC (NN / CH)   // 64 chunks per batch
#define NO (NC + 1)    // 65 offset rows (incl. grand total)
#define NFIX (BB * NO) // 520 fix blocks inside mid kernel
#define OG 16          // rows per block in out kernel
#define RB 128         // rank blocks per batch (r6-verified occupancy fix)

__device__ __forceinline__ float relu(float x) { return x > 0.f ? x : 0.f; }

typedef __attribute__((ext_vector_type(8))) __bf16 bf16x8;
typedef __attribute__((ext_vector_type(4))) float f32x4;

// split fp32 -> bf16 hi/lo (bf16x3 trick, fp32-quality accumulation)
__device__ __forceinline__ void cvt2(float x, __bf16& hi, __bf16& lo) {
    hi = (__bf16)x;
    lo = (__bf16)(x - (float)hi);
}

// ---------- Kernel 1': E=exp(h.u), F=exp(h.v) with u=W^T a_i, v=W^T a_j ----------
// r7: hw matrix eliminated. s_i = (h W^T) a_i = h (W^T a_i): each block
// redundantly computes u,v (W is L2-resident), then 32 rows of 2 GEMV dots.
__global__ __launch_bounds__(256) void GraphAttentionalLayer_1168231104632_kernel(
    const float* __restrict__ h,
    const float* __restrict__ W,
    const float* __restrict__ a,
    float* __restrict__ E,
    float* __restrict__ F)
{
    __shared__ float u_s[DD];
    __shared__ float v_s[DD];

    const int tid = threadIdx.x;
    const int b  = blockIdx.x >> 6;
    const int i0 = (blockIdx.x & 63) * 32;
    const size_t nb = (size_t)b * NN;

    {
        const int d = tid & 127;
        const float* av = (tid < DD) ? a : (a + DD);
        float acc = 0.f;
#pragma unroll 16
        for (int e = 0; e < DD; e++)
            acc += av[e] * W[(size_t)e * DD + d];   // coalesced across threads
        if (tid < DD) u_s[d] = acc; else v_s[d] = acc;
    }
    __syncthreads();

    const int row = tid >> 3;           // 0..31
    const int cb  = (tid & 7) * 4;
    const float* hrow = h + (nb + i0 + row) * DD;
    float pi = 0.f, pj = 0.f;
#pragma unroll
    for (int q = 0; q < 4; q++) {
        const int col = cb + q * 32;
        const float4 hv = *reinterpret_cast<const float4*>(&hrow[col]);
        const float4 uu = *reinterpret_cast<const float4*>(&u_s[col]);
        const float4 vv = *reinterpret_cast<const float4*>(&v_s[col]);
        pi += hv.x * uu.x + hv.y * uu.y + hv.z * uu.z + hv.w * uu.w;
        pj += hv.x * vv.x + hv.y * vv.y + hv.z * vv.z + hv.w * vv.w;
    }
#pragma unroll
    for (int off = 4; off > 0; off >>= 1) {
        pi += __shfl_down(pi, off, 8);
        pj += __shfl_down(pj, off, 8);
    }
    if ((tid & 7) == 0) {
        E[nb + i0 + row] = __expf(pi);
        F[nb + i0 + row] = __expf(pj);
    }
}

// ---------- Kernel 2: rank-sort, 1024 blocks (r6-verified) ----------
__global__ __launch_bounds__(256) void GraphAttentionalLayer_1168231104632_rank(
    const float* __restrict__ F,
    float* __restrict__ Fsorted,
    int* __restrict__ perm)
{
    __shared__ float F_s[NN];        // 8 KB
    __shared__ int   part[16][16];   // 1 KB

    const int t = threadIdx.x;
    const int b = blockIdx.x >> 7;           // 128 blocks per batch
    const int j0 = (blockIdx.x & (RB - 1)) * 16;
    const size_t nb = (size_t)b * NN;

    for (int q = 0; q < NN / 256; q++)
        F_s[q * 256 + t] = F[nb + q * 256 + t];
    __syncthreads();

    const int tj = t & 15, ts = t >> 4;      // 16 j's x 16 segments
    const int j = j0 + tj;
    const float fj = F_s[j];
    const int m0 = ts * (NN / 16);           // 128-element segment
    int cnt = 0;
    const float4* F4 = reinterpret_cast<const float4*>(&F_s[m0]);
#pragma unroll 8
    for (int mi4 = 0; mi4 < NN / 64; mi4++) {   // 32 float4 reads
        const float4 fm4 = F4[mi4];
        const int m = m0 + mi4 * 4;
        cnt += (fm4.x < fj) | ((fm4.x == fj) & (m     < j));
        cnt += (fm4.y < fj) | ((fm4.y == fj) & (m + 1 < j));
        cnt += (fm4.z < fj) | ((fm4.z == fj) & (m + 2 < j));
        cnt += (fm4.w < fj) | ((fm4.w == fj) & (m + 3 < j));
    }
    part[ts][tj] = cnt;
    __syncthreads();
    if (ts == 0) {
        int r = 0;
#pragma unroll
        for (int s = 0; s < 16; s++) r += part[s][tj];
        Fsorted[nb + r] = fj;
        perm[nb + r] = j;
    }
}

// ---------- Kernel 3': fused GEMM+scan per chunk ----------
// r7: block = 256 threads, chunk of 32 sorted rows. Phase A: bf16x3 MFMA
// GEMM on h rows gathered via perm (per-lane global addressing, no staging);
// B-frags from W (L2-resident). Phase B: scatter D to LDS. Phase C (t<128):
// sequential exclusive scans over the 32 rows, coalesced Q writes.
__global__ __launch_bounds__(256) void GraphAttentionalLayer_1168231104632_scan(
    const float* __restrict__ h,
    const float* __restrict__ W,
    const float* __restrict__ Fsorted,
    const int* __restrict__ perm,
    float* __restrict__ Q0L, float* __restrict__ Q1L,
    float* __restrict__ C0,  float* __restrict__ C1)
{
    __shared__ float hw_s[CH][HP];   // 16.9 KB
    __shared__ float fs_sh[CH];

    const int tid = threadIdx.x;
    const int lane = tid & 63;
    const int w  = tid >> 6;          // wave 0..3
    const int wm = w & 1;             // row half (16 rows)
    const int wn = w >> 1;            // col half (64 cols)
    const int lr = lane & 15;         // row (A) / col (B) within frag
    const int kg = lane >> 4;         // k-group: k = kg*8 + e
    const int b  = blockIdx.x >> 6;   // NC = 64 chunks/batch
    const int c  = blockIdx.x & 63;
    const size_t nb = (size_t)b * NN;
    const int m0 = c * CH;

    if (tid < CH) fs_sh[tid] = Fsorted[nb + m0 + tid];

    const int arow = wm * 16 + lr;                 // 0..31 within chunk
    const int jrow = perm[nb + m0 + arow];         // sorted gather index
    const float* hrow = h + (nb + jrow) * DD;

    f32x4 acc[4];
#pragma unroll
    for (int nf = 0; nf < 4; nf++) acc[nf] = (f32x4){0.f, 0.f, 0.f, 0.f};

#pragma unroll
    for (int kc = 0; kc < 4; kc++) {
        const int kb = kc * 32 + kg * 8;
        const float4 av0 = *reinterpret_cast<const float4*>(hrow + kb);
        const float4 av1 = *reinterpret_cast<const float4*>(hrow + kb + 4);
        const float av[8] = {av0.x, av0.y, av0.z, av0.w, av1.x, av1.y, av1.z, av1.w};
        bf16x8 ah, al;
#pragma unroll
        for (int e = 0; e < 8; e++) { __bf16 hi, lo; cvt2(av[e], hi, lo); ah[e] = hi; al[e] = lo; }

#pragma unroll
        for (int nf = 0; nf < 4; nf++) {
            const int wr = wn * 64 + nf * 16 + lr;     // W row = output col
            const float* wrow = W + (size_t)wr * DD + kb;
            const float4 bv0 = *reinterpret_cast<const float4*>(wrow);
            const float4 bv1 = *reinterpret_cast<const float4*>(wrow + 4);
            const float bv[8] = {bv0.x, bv0.y, bv0.z, bv0.w, bv1.x, bv1.y, bv1.z, bv1.w};
            bf16x8 bh, bl;
#pragma unroll
            for (int e = 0; e < 8; e++) { __bf16 hi, lo; cvt2(bv[e], hi, lo); bh[e] = hi; bl[e] = lo; }

            acc[nf] = __builtin_amdgcn_mfma_f32_16x16x32_bf16(ah, bh, acc[nf], 0, 0, 0);
            acc[nf] = __builtin_amdgcn_mfma_f32_16x16x32_bf16(ah, bl, acc[nf], 0, 0, 0);
            acc[nf] = __builtin_amdgcn_mfma_f32_16x16x32_bf16(al, bh, acc[nf], 0, 0, 0);
        }
    }

    // scatter D-frags to LDS: col = lr, row = kg*4 + r (verified C/D map)
#pragma unroll
    for (int nf = 0; nf < 4; nf++)
#pragma unroll
        for (int r = 0; r < 4; r++)
            hw_s[wm * 16 + kg * 4 + r][wn * 64 + nf * 16 + lr] = acc[nf][r];
    __syncthreads();

    // exclusive prefix scans over the chunk (dim-parallel, row-sequential)
    if (tid < DD) {
        const int t = tid;
        float a0 = 0.f, a1 = 0.f;
#pragma unroll
        for (int mm = 0; mm < CH; mm++) {
            const float hv = hw_s[mm][t];
            Q0L[(nb + m0 + mm) * DD + t] = a0;
            Q1L[(nb + m0 + mm) * DD + t] = a1;
            a0 += hv;
            a1 += fs_sh[mm] * hv;
        }
        C0[((size_t)b * NC + c) * DD + t] = a0;
        C1[((size_t)b * NC + c) * DD + t] = a1;
    }
}

// ---------- Kernel 4 (mid): fix offsets + parallel LDS search (r6-verified) ----------
__global__ __launch_bounds__(256) void GraphAttentionalLayer_1168231104632_mid(
    const float* __restrict__ C0, const float* __restrict__ C1,
    const float* __restrict__ Fsorted, const float* __restrict__ E,
    float* __restrict__ O0, float* __restrict__ O1,
    int* __restrict__ kk,  float* __restrict__ zinv)
{
    __shared__ float fs_s[NN];      // 8 KB
    __shared__ float cf_s[NC];
    __shared__ float of_s[NO];

    const int tid = threadIdx.x;

    if (blockIdx.x < NFIX) {
        const int b = blockIdx.x / NO, c = blockIdx.x % NO;
        const int d = tid & 127;
        const float* C = (tid < 128) ? C0 : C1;
        float*       O = (tid < 128) ? O0 : O1;
        float o = 0.f;
        int c2 = 0;
        for (; c2 + 16 <= c; c2 += 16) {
            float v[16];
#pragma unroll
            for (int q = 0; q < 16; q++)
                v[q] = C[((size_t)b * NC + c2 + q) * DD + d];
#pragma unroll
            for (int q = 0; q < 16; q++) o += v[q];
        }
        for (; c2 < c; c2++)
            o += C[((size_t)b * NC + c2) * DD + d];
        O[((size_t)b * NO + c) * DD + d] = o;
        return;
    }

    const int sb = blockIdx.x - NFIX;
    const int b = sb >> 3;
    const int i0 = (sb & 7) * 256;
    const size_t nb = (size_t)b * NN;

    for (int q = 0; q < NN / 256; q++)
        fs_s[q * 256 + tid] = Fsorted[nb + q * 256 + tid];
    __syncthreads();

    if (tid < NC) {
        float p = 0.f;
        const int m0 = tid * CH;
#pragma unroll
        for (int mm = 0; mm < CH; mm++) p += fs_s[m0 + mm];
        cf_s[tid] = p;
    }
    __syncthreads();
    if (tid < NO) {
        float p = 0.f;
        for (int c2 = 0; c2 < tid; c2++) p += cf_s[c2];
        of_s[tid] = p;
    }
    __syncthreads();

    const int row = (int)nb + i0 + tid;
    const float Ei = E[row];
    const float thr = 1.0f / Ei;
    int lo = 0, hi = NN;
    while (lo < hi) {
        const int mid = (lo + hi) >> 1;
        if (fs_s[mid] < thr) lo = mid + 1; else hi = mid;
    }
    float fpl = 0.f;
    for (int m = (lo >> 5) << 5; m < lo; m++) fpl += fs_s[m];
    const float TF = of_s[NC];
    const float Pk = of_s[lo >> 5] + fpl;
    const float z = Ei * (TF - Pk) + (float)lo;
    kk[row] = lo;
    zinv[row] = 1.0f / z;
}

// ---------- Kernel 5: output, 16 rows per 256-thread block (r6-verified) ----------
__global__ __launch_bounds__(256) void GraphAttentionalLayer_1168231104632_out(
    const float* __restrict__ Q0L, const float* __restrict__ Q1L,
    const float* __restrict__ O0,  const float* __restrict__ O1,
    const int* __restrict__ kk,    const float* __restrict__ zinv,
    const float* __restrict__ E,   float* __restrict__ out)
{
    const int tid = threadIdx.x;
    const int t  = tid & 127;            // d index
    const int rp = tid >> 7;             // row parity 0/1
    const int r0 = blockIdx.x * OG;      // first row of this block
    const int b  = r0 >> 11;             // batch (constant per block)
    const size_t nb = (size_t)b * NN;
    const float* O0b = O0 + (size_t)b * NO * DD;
    const float* O1b = O1 + (size_t)b * NO * DD;

    const float T1  = O1b[(size_t)NC * DD + t];   // batch totals
    const float TQ0 = O0b[(size_t)NC * DD + t];

#pragma unroll
    for (int q = 0; q < OG / 2; q++) {
        const int row = r0 + q * 2 + rp;
        const int k = kk[row];           // uniform across the row's 128 threads
        const float Ev = E[row];
        const float zv = zinv[row];

        float num;
        if (k < NN) {
            const int c = k >> 5;
            const float q0 = Q0L[(nb + k) * DD + t] + O0b[(size_t)c * DD + t];
            const float q1 = Q1L[(nb + k) * DD + t] + O1b[(size_t)c * DD + t];
            num = Ev * (T1 - q1) + q0;
        } else {
            num = TQ0;
        }
        out[(size_t)row * DD + t] = relu(num * zv);
    }
}

extern "C" __attribute__((visibility("default")))
void kernel_launch(void* const* d_in, const int* in_sizes, int n_in,
                   void* d_out, int out_size, void* d_ws, size_t ws_size,
                   hipStream_t stream) {
    const float* h = nullptr; const float* W = nullptr; const float* a = nullptr;
    for (int i = 0; i < n_in; i++) {
        if (in_sizes[i] == BB * NN * DD)      h = (const float*)d_in[i];
        else if (in_sizes[i] == DD * DD)      W = (const float*)d_in[i];
        else if (in_sizes[i] == 2 * DD)       a = (const float*)d_in[i];
    }
    if (!h) h = (const float*)d_in[0];
    if (!W) W = (const float*)d_in[1];
    if (!a) a = (const float*)d_in[2];

    float* out = (float*)d_out;
    float* ws = (float*)d_ws;

    // layout kept identical to r6 (hw slot now unused)
    float* hw   = ws;                              // 2,097,152 (unused, r7)
    float* E    = hw + (size_t)BB * NN * DD;       // 16,384
    float* F    = E + BB * NN;                     // 16,384
    float* Fs   = F + BB * NN;                     // 16,384
    float* zinv = Fs + BB * NN;                    // 16,384
    int*   perm = (int*)(zinv + BB * NN);          // 16,384
    int*   kk   = perm + BB * NN;                  // 16,384
    float* Q0L  = (float*)(kk + BB * NN);          // 2,097,152
    float* Q1L  = Q0L + (size_t)BB * NN * DD;      // 2,097,152
    float* C0   = Q1L + (size_t)BB * NN * DD;      // 65,536
    float* C1   = C0 + BB * NC * DD;               // 65,536
    float* O0   = C1 + BB * NC * DD;               // 66,560
    float* O1   = O0 + BB * NO * DD;               // 66,560
    const size_t need = (size_t)((O1 + BB * NO * DD) - ws) * sizeof(float); // ~26.3 MB

    if (ws_size < need || d_ws == nullptr) {
        hipMemsetAsync(d_out, 0x42, (size_t)out_size * sizeof(float), stream);
        return;
    }

    GraphAttentionalLayer_1168231104632_kernel<<<BB * 64, 256, 0, stream>>>(h, W, a, E, F);
    GraphAttentionalLayer_1168231104632_rank<<<BB * RB, 256, 0, stream>>>(F, Fs, perm);
    GraphAttentionalLayer_1168231104632_scan<<<BB * NC, 256, 0, stream>>>(h, W, Fs, perm, Q0L, Q1L, C0, C1);
    GraphAttentionalLayer_1168231104632_mid<<<NFIX + BB * 8, 256, 0, stream>>>(C0, C1, Fs, E, O0, O1, kk, zinv);
    GraphAttentionalLayer_1168231104632_out<<<(BB * NN) / OG, 256, 0, stream>>>(Q0L, Q1L, O0, O1, kk, zinv, E, out);
}

// Round 8
// 101.608 us; speedup vs baseline: 1.0154x; 1.0154x over previous
//
#include <hip/hip_runtime.h>
#include <hip/hip_bf16.h>

#define BB 8
#define NN 2048
#define DD 128
#define TI 32     // i-rows per GEMM block (256 threads)
#define HP 132    // padded row stride for 128-wide LDS tiles
#define CH 32     // chunk length
#define NC (NN / CH)   // 64 chunks per batch
#define NO (NC + 1)    // 65 offset rows (incl. grand total)
#define NFIX (BB * NO) // 520 fix blocks inside mid kernel
#define OG 16          // rows per block in out kernel
#define RB 128         // rank blocks per batch (r6-verified occupancy fix)
#define SG 4           // scan groups per chunk (r8 occupancy fix)
#define SR (CH / SG)   // rows per scan group = 8

__device__ __forceinline__ float relu(float x) { return x > 0.f ? x : 0.f; }

typedef __attribute__((ext_vector_type(8))) __bf16 bf16x8;
typedef __attribute__((ext_vector_type(4))) float f32x4;

// split fp32 -> bf16 hi/lo (bf16x3 trick, fp32-quality accumulation)
__device__ __forceinline__ void cvt2(float x, __bf16& hi, __bf16& lo) {
    hi = (__bf16)x;
    lo = (__bf16)(x - (float)hi);
}

// ---------- Kernel 1: hw = h@W^T (bf16x3 MFMA); E=exp(si), F=exp(sj) ----------
// r6-verified (absmax 0.00195, t ~= 5us). r7's hw-elimination regressed; reverted.
__global__ __launch_bounds__(256) void GraphAttentionalLayer_1168231104632_kernel(
    const float* __restrict__ h,
    const float* __restrict__ W,
    const float* __restrict__ a,
    float* __restrict__ hw,
    float* __restrict__ E,
    float* __restrict__ F)
{
    __shared__ float hw_s[TI][HP];    // 16.9 KB

    const int tid = threadIdx.x;
    const int lane = tid & 63;
    const int w  = tid >> 6;          // wave 0..3
    const int wm = w & 1;             // row half (16 rows)
    const int wn = w >> 1;            // col half (64 cols)
    const int lr = lane & 15;         // row (A) / col (B) within frag
    const int kg = lane >> 4;         // k-group: k = kg*8 + e
    const int b  = blockIdx.x >> 6;
    const int i0 = (blockIdx.x & 63) * TI;

    const int arow = i0 + wm * 16 + lr;
    const float* hrow = h + ((size_t)b * NN + arow) * DD;

    f32x4 acc[4];
#pragma unroll
    for (int nf = 0; nf < 4; nf++) acc[nf] = (f32x4){0.f, 0.f, 0.f, 0.f};

#pragma unroll
    for (int kc = 0; kc < 4; kc++) {
        const int kb = kc * 32 + kg * 8;
        const float4 av0 = *reinterpret_cast<const float4*>(hrow + kb);
        const float4 av1 = *reinterpret_cast<const float4*>(hrow + kb + 4);
        const float av[8] = {av0.x, av0.y, av0.z, av0.w, av1.x, av1.y, av1.z, av1.w};
        bf16x8 ah, al;
#pragma unroll
        for (int e = 0; e < 8; e++) { __bf16 hi, lo; cvt2(av[e], hi, lo); ah[e] = hi; al[e] = lo; }

#pragma unroll
        for (int nf = 0; nf < 4; nf++) {
            const int wr = wn * 64 + nf * 16 + lr;     // W row = output col
            const float* wrow = W + (size_t)wr * DD + kb;
            const float4 bv0 = *reinterpret_cast<const float4*>(wrow);
            const float4 bv1 = *reinterpret_cast<const float4*>(wrow + 4);
            const float bv[8] = {bv0.x, bv0.y, bv0.z, bv0.w, bv1.x, bv1.y, bv1.z, bv1.w};
            bf16x8 bh, bl;
#pragma unroll
            for (int e = 0; e < 8; e++) { __bf16 hi, lo; cvt2(bv[e], hi, lo); bh[e] = hi; bl[e] = lo; }

            acc[nf] = __builtin_amdgcn_mfma_f32_16x16x32_bf16(ah, bh, acc[nf], 0, 0, 0);
            acc[nf] = __builtin_amdgcn_mfma_f32_16x16x32_bf16(ah, bl, acc[nf], 0, 0, 0);
            acc[nf] = __builtin_amdgcn_mfma_f32_16x16x32_bf16(al, bh, acc[nf], 0, 0, 0);
        }
    }

    // scatter D-frags to LDS: col = lr, row = kg*4 + r (verified C/D map)
#pragma unroll
    for (int nf = 0; nf < 4; nf++)
#pragma unroll
        for (int r = 0; r < 4; r++)
            hw_s[wm * 16 + kg * 4 + r][wn * 64 + nf * 16 + lr] = acc[nf][r];
    __syncthreads();

    // coalesced hw write + fused E/F epilogue (8 threads per row)
    const int row = tid >> 3;
    const int cb  = (tid & 7) * 4;
    const size_t gbase = ((size_t)b * NN + i0 + row) * DD;
    float pi = 0.f, pj = 0.f;
#pragma unroll
    for (int qq = 0; qq < 4; qq++) {
        const int col = cb + qq * 32;
        const float4 v = *reinterpret_cast<const float4*>(&hw_s[row][col]);
        *reinterpret_cast<float4*>(&hw[gbase + col]) = v;
        const float4 avi = *reinterpret_cast<const float4*>(&a[col]);
        const float4 avj = *reinterpret_cast<const float4*>(&a[DD + col]);
        pi += v.x * avi.x + v.y * avi.y + v.z * avi.z + v.w * avi.w;
        pj += v.x * avj.x + v.y * avj.y + v.z * avj.z + v.w * avj.w;
    }
#pragma unroll
    for (int off = 4; off > 0; off >>= 1) {
        pi += __shfl_down(pi, off, 8);
        pj += __shfl_down(pj, off, 8);
    }
    if ((tid & 7) == 0) {
        const size_t rr = (size_t)b * NN + i0 + row;
        E[rr] = __expf(pi);
        F[rr] = __expf(pj);
    }
}

// ---------- Kernel 2: rank-sort, 1024 blocks (r6-verified) ----------
__global__ __launch_bounds__(256) void GraphAttentionalLayer_1168231104632_rank(
    const float* __restrict__ F,
    float* __restrict__ Fsorted,
    int* __restrict__ perm)
{
    __shared__ float F_s[NN];        // 8 KB
    __shared__ int   part[16][16];   // 1 KB

    const int t = threadIdx.x;
    const int b = blockIdx.x >> 7;           // 128 blocks per batch
    const int j0 = (blockIdx.x & (RB - 1)) * 16;
    const size_t nb = (size_t)b * NN;

    for (int q = 0; q < NN / 256; q++)
        F_s[q * 256 + t] = F[nb + q * 256 + t];
    __syncthreads();

    const int tj = t & 15, ts = t >> 4;      // 16 j's x 16 segments
    const int j = j0 + tj;
    const float fj = F_s[j];
    const int m0 = ts * (NN / 16);           // 128-element segment
    int cnt = 0;
    const float4* F4 = reinterpret_cast<const float4*>(&F_s[m0]);
#pragma unroll 8
    for (int mi4 = 0; mi4 < NN / 64; mi4++) {   // 32 float4 reads
        const float4 fm4 = F4[mi4];
        const int m = m0 + mi4 * 4;
        cnt += (fm4.x < fj) | ((fm4.x == fj) & (m     < j));
        cnt += (fm4.y < fj) | ((fm4.y == fj) & (m + 1 < j));
        cnt += (fm4.z < fj) | ((fm4.z == fj) & (m + 2 < j));
        cnt += (fm4.w < fj) | ((fm4.w == fj) & (m + 3 < j));
    }
    part[ts][tj] = cnt;
    __syncthreads();
    if (ts == 0) {
        int r = 0;
#pragma unroll
        for (int s = 0; s < 16; s++) r += part[s][tj];
        Fsorted[nb + r] = fj;
        perm[nb + r] = j;
    }
}

// ---------- Kernel 3: chunked prefix scans, 512 threads (r8 occupancy fix) ----------
// r6 version: 128 threads/block = 1 wave/SIMD, latency-bound (same pathology
// the r6 rank fix cured). r8: 512 threads, chunk split into 4 groups x 8 rows;
// group-local sums exchanged via LDS, each group writes its 8 Q-rows with the
// exclusive group offset. 4x parallelism, serial chain 32 -> 8 rows.
__global__ __launch_bounds__(512) void GraphAttentionalLayer_1168231104632_scan(
    const float* __restrict__ hw,
    const float* __restrict__ Fsorted,
    const int* __restrict__ perm,
    float* __restrict__ Q0L, float* __restrict__ Q1L,
    float* __restrict__ C0,  float* __restrict__ C1)
{
    __shared__ float gs0[SG][DD];    // 2 KB
    __shared__ float gs1[SG][DD];    // 2 KB

    const int tid = threadIdx.x;
    const int g = tid >> 7;          // group 0..3
    const int t = tid & 127;         // d index
    const int b = blockIdx.x >> 6, c = blockIdx.x & 63;   // NC = 64
    const size_t nb = (size_t)b * NN;
    const int m0 = c * CH + g * SR;  // this group's first row in sorted order

    int   jv[SR];
    float Fv[SR];
#pragma unroll
    for (int mm = 0; mm < SR; mm++) jv[mm] = perm[nb + m0 + mm];
#pragma unroll
    for (int mm = 0; mm < SR; mm++) Fv[mm] = Fsorted[nb + m0 + mm];

    float hv[SR];
#pragma unroll
    for (int mm = 0; mm < SR; mm++)
        hv[mm] = hw[(nb + jv[mm]) * DD + t];

    float s0 = 0.f, s1 = 0.f;
#pragma unroll
    for (int mm = 0; mm < SR; mm++) { s0 += hv[mm]; s1 += Fv[mm] * hv[mm]; }
    gs0[g][t] = s0;
    gs1[g][t] = s1;
    __syncthreads();

    float a0 = 0.f, a1 = 0.f;
#pragma unroll
    for (int gg = 0; gg < SG - 1; gg++)
        if (gg < g) { a0 += gs0[gg][t]; a1 += gs1[gg][t]; }

#pragma unroll
    for (int mm = 0; mm < SR; mm++) {
        Q0L[(nb + m0 + mm) * DD + t] = a0;
        Q1L[(nb + m0 + mm) * DD + t] = a1;
        a0 += hv[mm];
        a1 += Fv[mm] * hv[mm];
    }
    if (g == SG - 1) {
        C0[((size_t)b * NC + c) * DD + t] = a0;   // full chunk sums
        C1[((size_t)b * NC + c) * DD + t] = a1;
    }
}

// ---------- Kernel 4 (mid): fix offsets + parallel LDS search (r6-verified) ----------
__global__ __launch_bounds__(256) void GraphAttentionalLayer_1168231104632_mid(
    const float* __restrict__ C0, const float* __restrict__ C1,
    const float* __restrict__ Fsorted, const float* __restrict__ E,
    float* __restrict__ O0, float* __restrict__ O1,
    int* __restrict__ kk,  float* __restrict__ zinv)
{
    __shared__ float fs_s[NN];      // 8 KB
    __shared__ float cf_s[NC];
    __shared__ float of_s[NO];

    const int tid = threadIdx.x;

    if (blockIdx.x < NFIX) {
        const int b = blockIdx.x / NO, c = blockIdx.x % NO;
        const int d = tid & 127;
        const float* C = (tid < 128) ? C0 : C1;
        float*       O = (tid < 128) ? O0 : O1;
        float o = 0.f;
        int c2 = 0;
        for (; c2 + 16 <= c; c2 += 16) {
            float v[16];
#pragma unroll
            for (int q = 0; q < 16; q++)
                v[q] = C[((size_t)b * NC + c2 + q) * DD + d];
#pragma unroll
            for (int q = 0; q < 16; q++) o += v[q];
        }
        for (; c2 < c; c2++)
            o += C[((size_t)b * NC + c2) * DD + d];
        O[((size_t)b * NO + c) * DD + d] = o;
        return;
    }

    const int sb = blockIdx.x - NFIX;
    const int b = sb >> 3;
    const int i0 = (sb & 7) * 256;
    const size_t nb = (size_t)b * NN;

    for (int q = 0; q < NN / 256; q++)
        fs_s[q * 256 + tid] = Fsorted[nb + q * 256 + tid];
    __syncthreads();

    if (tid < NC) {
        float p = 0.f;
        const int m0 = tid * CH;
#pragma unroll
        for (int mm = 0; mm < CH; mm++) p += fs_s[m0 + mm];
        cf_s[tid] = p;
    }
    __syncthreads();
    if (tid < NO) {
        float p = 0.f;
        for (int c2 = 0; c2 < tid; c2++) p += cf_s[c2];
        of_s[tid] = p;
    }
    __syncthreads();

    const int row = (int)nb + i0 + tid;
    const float Ei = E[row];
    const float thr = 1.0f / Ei;
    int lo = 0, hi = NN;
    while (lo < hi) {
        const int mid = (lo + hi) >> 1;
        if (fs_s[mid] < thr) lo = mid + 1; else hi = mid;
    }
    float fpl = 0.f;
    for (int m = (lo >> 5) << 5; m < lo; m++) fpl += fs_s[m];
    const float TF = of_s[NC];
    const float Pk = of_s[lo >> 5] + fpl;
    const float z = Ei * (TF - Pk) + (float)lo;
    kk[row] = lo;
    zinv[row] = 1.0f / z;
}

// ---------- Kernel 5: output, 16 rows per 256-thread block (r6-verified) ----------
__global__ __launch_bounds__(256) void GraphAttentionalLayer_1168231104632_out(
    const float* __restrict__ Q0L, const float* __restrict__ Q1L,
    const float* __restrict__ O0,  const float* __restrict__ O1,
    const int* __restrict__ kk,    const float* __restrict__ zinv,
    const float* __restrict__ E,   float* __restrict__ out)
{
    const int tid = threadIdx.x;
    const int t  = tid & 127;            // d index
    const int rp = tid >> 7;             // row parity 0/1
    const int r0 = blockIdx.x * OG;      // first row of this block
    const int b  = r0 >> 11;             // batch (constant per block)
    const size_t nb = (size_t)b * NN;
    const float* O0b = O0 + (size_t)b * NO * DD;
    const float* O1b = O1 + (size_t)b * NO * DD;

    const float T1  = O1b[(size_t)NC * DD + t];   // batch totals
    const float TQ0 = O0b[(size_t)NC * DD + t];

#pragma unroll
    for (int q = 0; q < OG / 2; q++) {
        const int row = r0 + q * 2 + rp;
        const int k = kk[row];           // uniform across the row's 128 threads
        const float Ev = E[row];
        const float zv = zinv[row];

        float num;
        if (k < NN) {
            const int c = k >> 5;
            const float q0 = Q0L[(nb + k) * DD + t] + O0b[(size_t)c * DD + t];
            const float q1 = Q1L[(nb + k) * DD + t] + O1b[(size_t)c * DD + t];
            num = Ev * (T1 - q1) + q0;
        } else {
            num = TQ0;
        }
        out[(size_t)row * DD + t] = relu(num * zv);
    }
}

extern "C" __attribute__((visibility("default")))
void kernel_launch(void* const* d_in, const int* in_sizes, int n_in,
                   void* d_out, int out_size, void* d_ws, size_t ws_size,
                   hipStream_t stream) {
    const float* h = nullptr; const float* W = nullptr; const float* a = nullptr;
    for (int i = 0; i < n_in; i++) {
        if (in_sizes[i] == BB * NN * DD)      h = (const float*)d_in[i];
        else if (in_sizes[i] == DD * DD)      W = (const float*)d_in[i];
        else if (in_sizes[i] == 2 * DD)       a = (const float*)d_in[i];
    }
    if (!h) h = (const float*)d_in[0];
    if (!W) W = (const float*)d_in[1];
    if (!a) a = (const float*)d_in[2];

    float* out = (float*)d_out;
    float* ws = (float*)d_ws;

    float* hw   = ws;                              // 2,097,152
    float* E    = hw + (size_t)BB * NN * DD;       // 16,384
    float* F    = E + BB * NN;                     // 16,384
    float* Fs   = F + BB * NN;                     // 16,384
    float* zinv = Fs + BB * NN;                    // 16,384
    int*   perm = (int*)(zinv + BB * NN);          // 16,384
    int*   kk   = perm + BB * NN;                  // 16,384
    float* Q0L  = (float*)(kk + BB * NN);          // 2,097,152
    float* Q1L  = Q0L + (size_t)BB * NN * DD;      // 2,097,152
    float* C0   = Q1L + (size_t)BB * NN * DD;      // 65,536
    float* C1   = C0 + BB * NC * DD;               // 65,536
    float* O0   = C1 + BB * NC * DD;               // 66,560
    float* O1   = O0 + BB * NO * DD;               // 66,560
    const size_t need = (size_t)((O1 + BB * NO * DD) - ws) * sizeof(float); // ~26.3 MB

    if (ws_size < need || d_ws == nullptr) {
        hipMemsetAsync(d_out, 0x42, (size_t)out_size * sizeof(float), stream);
        return;
    }

    GraphAttentionalLayer_1168231104632_kernel<<<BB * (NN / TI), 256, 0, stream>>>(h, W, a, hw, E, F);
    GraphAttentionalLayer_1168231104632_rank<<<BB * RB, 256, 0, stream>>>(F, Fs, perm);
    GraphAttentionalLayer_1168231104632_scan<<<BB * NC, 512, 0, stream>>>(hw, Fs, perm, Q0L, Q1L, C0, C1);
    GraphAttentionalLayer_1168231104632_mid<<<NFIX + BB * 8, 256, 0, stream>>>(C0, C1, Fs, E, O0, O1, kk, zinv);
    GraphAttentionalLayer_1168231104632_out<<<(BB * NN) / OG, 256, 0, stream>>>(Q0L, Q1L, O0, O1, kk, zinv, E, out);
}

// Round 9
// 101.067 us; speedup vs baseline: 1.0208x; 1.0054x over previous
//
#include <hip/hip_runtime.h>
#include <hip/hip_bf16.h>

#define BB 8
#define NN 2048
#define DD 128
#define TI 32     // i-rows per GEMM block (256 threads)
#define HP 132    // padded row stride for 128-wide LDS tiles
#define CH 32     // chunk length
#define NC (NN / CH)   // 64 chunks per batch
#define NO (NC + 1)    // 65 offset rows (incl. grand total)
#define NFIX (BB * NO) // 520 fix blocks inside mid kernel
#define OG 16          // rows per block in out kernel
#define RB 128         // rank blocks per batch (r6-verified occupancy fix)

__device__ __forceinline__ float relu(float x) { return x > 0.f ? x : 0.f; }

typedef __attribute__((ext_vector_type(8))) __bf16 bf16x8;
typedef __attribute__((ext_vector_type(4))) float f32x4;

// split fp32 -> bf16 hi/lo (bf16x3 trick, fp32-quality accumulation)
__device__ __forceinline__ void cvt2(float x, __bf16& hi, __bf16& lo) {
    hi = (__bf16)x;
    lo = (__bf16)(x - (float)hi);
}

// ---------- Kernel 1: hw = h@W^T (bf16x3 MFMA); E=exp(si), F=exp(sj) ----------
// r6-verified (absmax 0.00195, t ~= 5.5us).
__global__ __launch_bounds__(256) void GraphAttentionalLayer_1168231104632_kernel(
    const float* __restrict__ h,
    const float* __restrict__ W,
    const float* __restrict__ a,
    float* __restrict__ hw,
    float* __restrict__ E,
    float* __restrict__ F)
{
    __shared__ float hw_s[TI][HP];    // 16.9 KB

    const int tid = threadIdx.x;
    const int lane = tid & 63;
    const int w  = tid >> 6;          // wave 0..3
    const int wm = w & 1;             // row half (16 rows)
    const int wn = w >> 1;            // col half (64 cols)
    const int lr = lane & 15;         // row (A) / col (B) within frag
    const int kg = lane >> 4;         // k-group: k = kg*8 + e
    const int b  = blockIdx.x >> 6;
    const int i0 = (blockIdx.x & 63) * TI;

    const int arow = i0 + wm * 16 + lr;
    const float* hrow = h + ((size_t)b * NN + arow) * DD;

    f32x4 acc[4];
#pragma unroll
    for (int nf = 0; nf < 4; nf++) acc[nf] = (f32x4){0.f, 0.f, 0.f, 0.f};

#pragma unroll
    for (int kc = 0; kc < 4; kc++) {
        const int kb = kc * 32 + kg * 8;
        const float4 av0 = *reinterpret_cast<const float4*>(hrow + kb);
        const float4 av1 = *reinterpret_cast<const float4*>(hrow + kb + 4);
        const float av[8] = {av0.x, av0.y, av0.z, av0.w, av1.x, av1.y, av1.z, av1.w};
        bf16x8 ah, al;
#pragma unroll
        for (int e = 0; e < 8; e++) { __bf16 hi, lo; cvt2(av[e], hi, lo); ah[e] = hi; al[e] = lo; }

#pragma unroll
        for (int nf = 0; nf < 4; nf++) {
            const int wr = wn * 64 + nf * 16 + lr;     // W row = output col
            const float* wrow = W + (size_t)wr * DD + kb;
            const float4 bv0 = *reinterpret_cast<const float4*>(wrow);
            const float4 bv1 = *reinterpret_cast<const float4*>(wrow + 4);
            const float bv[8] = {bv0.x, bv0.y, bv0.z, bv0.w, bv1.x, bv1.y, bv1.z, bv1.w};
            bf16x8 bh, bl;
#pragma unroll
            for (int e = 0; e < 8; e++) { __bf16 hi, lo; cvt2(bv[e], hi, lo); bh[e] = hi; bl[e] = lo; }

            acc[nf] = __builtin_amdgcn_mfma_f32_16x16x32_bf16(ah, bh, acc[nf], 0, 0, 0);
            acc[nf] = __builtin_amdgcn_mfma_f32_16x16x32_bf16(ah, bl, acc[nf], 0, 0, 0);
            acc[nf] = __builtin_amdgcn_mfma_f32_16x16x32_bf16(al, bh, acc[nf], 0, 0, 0);
        }
    }

    // scatter D-frags to LDS: col = lr, row = kg*4 + r (verified C/D map)
#pragma unroll
    for (int nf = 0; nf < 4; nf++)
#pragma unroll
        for (int r = 0; r < 4; r++)
            hw_s[wm * 16 + kg * 4 + r][wn * 64 + nf * 16 + lr] = acc[nf][r];
    __syncthreads();

    // coalesced hw write + fused E/F epilogue (8 threads per row)
    const int row = tid >> 3;
    const int cb  = (tid & 7) * 4;
    const size_t gbase = ((size_t)b * NN + i0 + row) * DD;
    float pi = 0.f, pj = 0.f;
#pragma unroll
    for (int qq = 0; qq < 4; qq++) {
        const int col = cb + qq * 32;
        const float4 v = *reinterpret_cast<const float4*>(&hw_s[row][col]);
        *reinterpret_cast<float4*>(&hw[gbase + col]) = v;
        const float4 avi = *reinterpret_cast<const float4*>(&a[col]);
        const float4 avj = *reinterpret_cast<const float4*>(&a[DD + col]);
        pi += v.x * avi.x + v.y * avi.y + v.z * avi.z + v.w * avi.w;
        pj += v.x * avj.x + v.y * avj.y + v.z * avj.z + v.w * avj.w;
    }
#pragma unroll
    for (int off = 4; off > 0; off >>= 1) {
        pi += __shfl_down(pi, off, 8);
        pj += __shfl_down(pj, off, 8);
    }
    if ((tid & 7) == 0) {
        const size_t rr = (size_t)b * NN + i0 + row;
        E[rr] = __expf(pi);
        F[rr] = __expf(pj);
    }
}

// ---------- Kernel 2: rank-sort, 1024 blocks (r6-verified) ----------
__global__ __launch_bounds__(256) void GraphAttentionalLayer_1168231104632_rank(
    const float* __restrict__ F,
    float* __restrict__ Fsorted,
    int* __restrict__ perm)
{
    __shared__ float F_s[NN];        // 8 KB
    __shared__ int   part[16][16];   // 1 KB

    const int t = threadIdx.x;
    const int b = blockIdx.x >> 7;           // 128 blocks per batch
    const int j0 = (blockIdx.x & (RB - 1)) * 16;
    const size_t nb = (size_t)b * NN;

    for (int q = 0; q < NN / 256; q++)
        F_s[q * 256 + t] = F[nb + q * 256 + t];
    __syncthreads();

    const int tj = t & 15, ts = t >> 4;      // 16 j's x 16 segments
    const int j = j0 + tj;
    const float fj = F_s[j];
    const int m0 = ts * (NN / 16);           // 128-element segment
    int cnt = 0;
    const float4* F4 = reinterpret_cast<const float4*>(&F_s[m0]);
#pragma unroll 8
    for (int mi4 = 0; mi4 < NN / 64; mi4++) {   // 32 float4 reads
        const float4 fm4 = F4[mi4];
        const int m = m0 + mi4 * 4;
        cnt += (fm4.x < fj) | ((fm4.x == fj) & (m     < j));
        cnt += (fm4.y < fj) | ((fm4.y == fj) & (m + 1 < j));
        cnt += (fm4.z < fj) | ((fm4.z == fj) & (m + 2 < j));
        cnt += (fm4.w < fj) | ((fm4.w == fj) & (m + 3 < j));
    }
    part[ts][tj] = cnt;
    __syncthreads();
    if (ts == 0) {
        int r = 0;
#pragma unroll
        for (int s = 0; s < 16; s++) r += part[s][tj];
        Fsorted[nb + r] = fj;
        perm[nb + r] = j;
    }
}

// ---------- Kernel 3: chunked prefix scans (r6 structure + float2 QL) ----------
// r8's 512-thread restructure regressed (+2.3us) -> reverted to the r6 128-thread
// form (32-deep independent gather batch = the right shape for this stream-bound
// kernel). r9 change: Q0/Q1 interleaved as float2 into one QL buffer -> single
// contiguous 1KB-per-row store stream instead of two 512B streams 8MB apart.
__global__ __launch_bounds__(128) void GraphAttentionalLayer_1168231104632_scan(
    const float* __restrict__ hw,
    const float* __restrict__ Fsorted,
    const int* __restrict__ perm,
    float* __restrict__ QL,
    float* __restrict__ C0,  float* __restrict__ C1)
{
    const int t = threadIdx.x;
    const int b = blockIdx.x / NC, c = blockIdx.x % NC;
    const size_t nb = (size_t)b * NN;
    const int m0 = c * CH;

    int   jv[CH];
    float Fv[CH];
#pragma unroll
    for (int mm = 0; mm < CH; mm++) jv[mm] = perm[nb + m0 + mm];
#pragma unroll
    for (int mm = 0; mm < CH; mm++) Fv[mm] = Fsorted[nb + m0 + mm];

    float hv[CH];
#pragma unroll
    for (int mm = 0; mm < CH; mm++)
        hv[mm] = hw[(nb + jv[mm]) * DD + t];

    float a0 = 0.f, a1 = 0.f;
#pragma unroll
    for (int mm = 0; mm < CH; mm++) {
        const size_t m = nb + m0 + mm;
        *reinterpret_cast<float2*>(&QL[(m * DD + t) * 2]) = make_float2(a0, a1);
        a0 += hv[mm];
        a1 += Fv[mm] * hv[mm];
    }
    C0[((size_t)b * NC + c) * DD + t] = a0;
    C1[((size_t)b * NC + c) * DD + t] = a1;
}

// ---------- Kernel 4 (mid): fix offsets + parallel LDS search (r6-verified) ----------
__global__ __launch_bounds__(256) void GraphAttentionalLayer_1168231104632_mid(
    const float* __restrict__ C0, const float* __restrict__ C1,
    const float* __restrict__ Fsorted, const float* __restrict__ E,
    float* __restrict__ O0, float* __restrict__ O1,
    int* __restrict__ kk,  float* __restrict__ zinv)
{
    __shared__ float fs_s[NN];      // 8 KB
    __shared__ float cf_s[NC];
    __shared__ float of_s[NO];

    const int tid = threadIdx.x;

    if (blockIdx.x < NFIX) {
        const int b = blockIdx.x / NO, c = blockIdx.x % NO;
        const int d = tid & 127;
        const float* C = (tid < 128) ? C0 : C1;
        float*       O = (tid < 128) ? O0 : O1;
        float o = 0.f;
        int c2 = 0;
        for (; c2 + 16 <= c; c2 += 16) {
            float v[16];
#pragma unroll
            for (int q = 0; q < 16; q++)
                v[q] = C[((size_t)b * NC + c2 + q) * DD + d];
#pragma unroll
            for (int q = 0; q < 16; q++) o += v[q];
        }
        for (; c2 < c; c2++)
            o += C[((size_t)b * NC + c2) * DD + d];
        O[((size_t)b * NO + c) * DD + d] = o;
        return;
    }

    const int sb = blockIdx.x - NFIX;
    const int b = sb >> 3;
    const int i0 = (sb & 7) * 256;
    const size_t nb = (size_t)b * NN;

    for (int q = 0; q < NN / 256; q++)
        fs_s[q * 256 + tid] = Fsorted[nb + q * 256 + tid];
    __syncthreads();

    if (tid < NC) {
        float p = 0.f;
        const int m0 = tid * CH;
#pragma unroll
        for (int mm = 0; mm < CH; mm++) p += fs_s[m0 + mm];
        cf_s[tid] = p;
    }
    __syncthreads();
    if (tid < NO) {
        float p = 0.f;
        for (int c2 = 0; c2 < tid; c2++) p += cf_s[c2];
        of_s[tid] = p;
    }
    __syncthreads();

    const int row = (int)nb + i0 + tid;
    const float Ei = E[row];
    const float thr = 1.0f / Ei;
    int lo = 0, hi = NN;
    while (lo < hi) {
        const int mid = (lo + hi) >> 1;
        if (fs_s[mid] < thr) lo = mid + 1; else hi = mid;
    }
    float fpl = 0.f;
    for (int m = (lo >> 5) << 5; m < lo; m++) fpl += fs_s[m];
    const float TF = of_s[NC];
    const float Pk = of_s[lo >> 5] + fpl;
    const float z = Ei * (TF - Pk) + (float)lo;
    kk[row] = lo;
    zinv[row] = 1.0f / z;
}

// ---------- Kernel 5: output, 16 rows per 256-thread block (r6 + float2 QL) ----------
__global__ __launch_bounds__(256) void GraphAttentionalLayer_1168231104632_out(
    const float* __restrict__ QL,
    const float* __restrict__ O0,  const float* __restrict__ O1,
    const int* __restrict__ kk,    const float* __restrict__ zinv,
    const float* __restrict__ E,   float* __restrict__ out)
{
    const int tid = threadIdx.x;
    const int t  = tid & 127;            // d index
    const int rp = tid >> 7;             // row parity 0/1
    const int r0 = blockIdx.x * OG;      // first row of this block
    const int b  = r0 >> 11;             // batch (constant per block)
    const size_t nb = (size_t)b * NN;
    const float* O0b = O0 + (size_t)b * NO * DD;
    const float* O1b = O1 + (size_t)b * NO * DD;

    const float T1  = O1b[(size_t)NC * DD + t];   // batch totals
    const float TQ0 = O0b[(size_t)NC * DD + t];

#pragma unroll
    for (int q = 0; q < OG / 2; q++) {
        const int row = r0 + q * 2 + rp;
        const int k = kk[row];           // uniform across the row's 128 threads
        const float Ev = E[row];
        const float zv = zinv[row];

        float num;
        if (k < NN) {
            const int c = k >> 5;
            const float2 qv = *reinterpret_cast<const float2*>(&QL[((nb + k) * DD + t) * 2]);
            const float q0 = qv.x + O0b[(size_t)c * DD + t];
            const float q1 = qv.y + O1b[(size_t)c * DD + t];
            num = Ev * (T1 - q1) + q0;
        } else {
            num = TQ0;
        }
        out[(size_t)row * DD + t] = relu(num * zv);
    }
}

extern "C" __attribute__((visibility("default")))
void kernel_launch(void* const* d_in, const int* in_sizes, int n_in,
                   void* d_out, int out_size, void* d_ws, size_t ws_size,
                   hipStream_t stream) {
    const float* h = nullptr; const float* W = nullptr; const float* a = nullptr;
    for (int i = 0; i < n_in; i++) {
        if (in_sizes[i] == BB * NN * DD)      h = (const float*)d_in[i];
        else if (in_sizes[i] == DD * DD)      W = (const float*)d_in[i];
        else if (in_sizes[i] == 2 * DD)       a = (const float*)d_in[i];
    }
    if (!h) h = (const float*)d_in[0];
    if (!W) W = (const float*)d_in[1];
    if (!a) a = (const float*)d_in[2];

    float* out = (float*)d_out;
    float* ws = (float*)d_ws;

    float* hw   = ws;                              // 2,097,152
    float* E    = hw + (size_t)BB * NN * DD;       // 16,384
    float* F    = E + BB * NN;                     // 16,384
    float* Fs   = F + BB * NN;                     // 16,384
    float* zinv = Fs + BB * NN;                    // 16,384
    int*   perm = (int*)(zinv + BB * NN);          // 16,384
    int*   kk   = perm + BB * NN;                  // 16,384
    float* QL   = (float*)(kk + BB * NN);          // 4,194,304 (Q0/Q1 interleaved)
    float* C0   = QL + (size_t)2 * BB * NN * DD;   // 65,536
    float* C1   = C0 + BB * NC * DD;               // 65,536
    float* O0   = C1 + BB * NC * DD;               // 66,560
    float* O1   = O0 + BB * NO * DD;               // 66,560
    const size_t need = (size_t)((O1 + BB * NO * DD) - ws) * sizeof(float); // ~26.3 MB

    if (ws_size < need || d_ws == nullptr) {
        hipMemsetAsync(d_out, 0x42, (size_t)out_size * sizeof(float), stream);
        return;
    }

    GraphAttentionalLayer_1168231104632_kernel<<<BB * (NN / TI), 256, 0, stream>>>(h, W, a, hw, E, F);
    GraphAttentionalLayer_1168231104632_rank<<<BB * RB, 256, 0, stream>>>(F, Fs, perm);
    GraphAttentionalLayer_1168231104632_scan<<<BB * NC, 128, 0, stream>>>(hw, Fs, perm, QL, C0, C1);
    GraphAttentionalLayer_1168231104632_mid<<<NFIX + BB * 8, 256, 0, stream>>>(C0, C1, Fs, E, O0, O1, kk, zinv);
    GraphAttentionalLayer_1168231104632_out<<<(BB * NN) / OG, 256, 0, stream>>>(QL, O0, O1, kk, zinv, E, out);
}

// Round 10
// 100.053 us; speedup vs baseline: 1.0312x; 1.0101x over previous
//
#include <hip/hip_runtime.h>
#include <hip/hip_bf16.h>

#define BB 8
#define NN 2048
#define DD 128
#define TI 32     // i-rows per GEMM block (256 threads)
#define HP 132    // padded row stride for 128-wide LDS tiles
#define CH 32     // chunk length
#define NC (NN / CH)   // 64 chunks per batch
#define NO (NC + 1)    // 65 offset rows (incl. grand total)
#define NFIX (BB * NO) // 520 fix blocks inside mid kernel
#define OG 16          // rows per block in out kernel
#define RB 128         // rank blocks per batch (r6-verified occupancy fix)

__device__ __forceinline__ float relu(float x) { return x > 0.f ? x : 0.f; }

typedef __attribute__((ext_vector_type(8))) __bf16 bf16x8;
typedef __attribute__((ext_vector_type(4))) float f32x4;

// split fp32 -> bf16 hi/lo (bf16x3 trick, fp32-quality accumulation)
__device__ __forceinline__ void cvt2(float x, __bf16& hi, __bf16& lo) {
    hi = (__bf16)x;
    lo = (__bf16)(x - (float)hi);
}

// ---------- Kernel 1: hw = h@W^T (bf16x3 MFMA); E=exp(si), F=exp(sj) ----------
// r6-verified (absmax 0.00195, t ~= 5.5us).
__global__ __launch_bounds__(256) void GraphAttentionalLayer_1168231104632_kernel(
    const float* __restrict__ h,
    const float* __restrict__ W,
    const float* __restrict__ a,
    float* __restrict__ hw,
    float* __restrict__ E,
    float* __restrict__ F)
{
    __shared__ float hw_s[TI][HP];    // 16.9 KB

    const int tid = threadIdx.x;
    const int lane = tid & 63;
    const int w  = tid >> 6;          // wave 0..3
    const int wm = w & 1;             // row half (16 rows)
    const int wn = w >> 1;            // col half (64 cols)
    const int lr = lane & 15;         // row (A) / col (B) within frag
    const int kg = lane >> 4;         // k-group: k = kg*8 + e
    const int b  = blockIdx.x >> 6;
    const int i0 = (blockIdx.x & 63) * TI;

    const int arow = i0 + wm * 16 + lr;
    const float* hrow = h + ((size_t)b * NN + arow) * DD;

    f32x4 acc[4];
#pragma unroll
    for (int nf = 0; nf < 4; nf++) acc[nf] = (f32x4){0.f, 0.f, 0.f, 0.f};

#pragma unroll
    for (int kc = 0; kc < 4; kc++) {
        const int kb = kc * 32 + kg * 8;
        const float4 av0 = *reinterpret_cast<const float4*>(hrow + kb);
        const float4 av1 = *reinterpret_cast<const float4*>(hrow + kb + 4);
        const float av[8] = {av0.x, av0.y, av0.z, av0.w, av1.x, av1.y, av1.z, av1.w};
        bf16x8 ah, al;
#pragma unroll
        for (int e = 0; e < 8; e++) { __bf16 hi, lo; cvt2(av[e], hi, lo); ah[e] = hi; al[e] = lo; }

#pragma unroll
        for (int nf = 0; nf < 4; nf++) {
            const int wr = wn * 64 + nf * 16 + lr;     // W row = output col
            const float* wrow = W + (size_t)wr * DD + kb;
            const float4 bv0 = *reinterpret_cast<const float4*>(wrow);
            const float4 bv1 = *reinterpret_cast<const float4*>(wrow + 4);
            const float bv[8] = {bv0.x, bv0.y, bv0.z, bv0.w, bv1.x, bv1.y, bv1.z, bv1.w};
            bf16x8 bh, bl;
#pragma unroll
            for (int e = 0; e < 8; e++) { __bf16 hi, lo; cvt2(bv[e], hi, lo); bh[e] = hi; bl[e] = lo; }

            acc[nf] = __builtin_amdgcn_mfma_f32_16x16x32_bf16(ah, bh, acc[nf], 0, 0, 0);
            acc[nf] = __builtin_amdgcn_mfma_f32_16x16x32_bf16(ah, bl, acc[nf], 0, 0, 0);
            acc[nf] = __builtin_amdgcn_mfma_f32_16x16x32_bf16(al, bh, acc[nf], 0, 0, 0);
        }
    }

    // scatter D-frags to LDS: col = lr, row = kg*4 + r (verified C/D map)
#pragma unroll
    for (int nf = 0; nf < 4; nf++)
#pragma unroll
        for (int r = 0; r < 4; r++)
            hw_s[wm * 16 + kg * 4 + r][wn * 64 + nf * 16 + lr] = acc[nf][r];
    __syncthreads();

    // coalesced hw write + fused E/F epilogue (8 threads per row)
    const int row = tid >> 3;
    const int cb  = (tid & 7) * 4;
    const size_t gbase = ((size_t)b * NN + i0 + row) * DD;
    float pi = 0.f, pj = 0.f;
#pragma unroll
    for (int qq = 0; qq < 4; qq++) {
        const int col = cb + qq * 32;
        const float4 v = *reinterpret_cast<const float4*>(&hw_s[row][col]);
        *reinterpret_cast<float4*>(&hw[gbase + col]) = v;
        const float4 avi = *reinterpret_cast<const float4*>(&a[col]);
        const float4 avj = *reinterpret_cast<const float4*>(&a[DD + col]);
        pi += v.x * avi.x + v.y * avi.y + v.z * avi.z + v.w * avi.w;
        pj += v.x * avj.x + v.y * avj.y + v.z * avj.z + v.w * avj.w;
    }
#pragma unroll
    for (int off = 4; off > 0; off >>= 1) {
        pi += __shfl_down(pi, off, 8);
        pj += __shfl_down(pj, off, 8);
    }
    if ((tid & 7) == 0) {
        const size_t rr = (size_t)b * NN + i0 + row;
        E[rr] = __expf(pi);
        F[rr] = __expf(pj);
    }
}

// ---------- Kernel 2: rank-sort, 1024 blocks (r6-verified) ----------
__global__ __launch_bounds__(256) void GraphAttentionalLayer_1168231104632_rank(
    const float* __restrict__ F,
    float* __restrict__ Fsorted,
    int* __restrict__ perm)
{
    __shared__ float F_s[NN];        // 8 KB
    __shared__ int   part[16][16];   // 1 KB

    const int t = threadIdx.x;
    const int b = blockIdx.x >> 7;           // 128 blocks per batch
    const int j0 = (blockIdx.x & (RB - 1)) * 16;
    const size_t nb = (size_t)b * NN;

    for (int q = 0; q < NN / 256; q++)
        F_s[q * 256 + t] = F[nb + q * 256 + t];
    __syncthreads();

    const int tj = t & 15, ts = t >> 4;      // 16 j's x 16 segments
    const int j = j0 + tj;
    const float fj = F_s[j];
    const int m0 = ts * (NN / 16);           // 128-element segment
    int cnt = 0;
    const float4* F4 = reinterpret_cast<const float4*>(&F_s[m0]);
#pragma unroll 8
    for (int mi4 = 0; mi4 < NN / 64; mi4++) {   // 32 float4 reads
        const float4 fm4 = F4[mi4];
        const int m = m0 + mi4 * 4;
        cnt += (fm4.x < fj) | ((fm4.x == fj) & (m     < j));
        cnt += (fm4.y < fj) | ((fm4.y == fj) & (m + 1 < j));
        cnt += (fm4.z < fj) | ((fm4.z == fj) & (m + 2 < j));
        cnt += (fm4.w < fj) | ((fm4.w == fj) & (m + 3 < j));
    }
    part[ts][tj] = cnt;
    __syncthreads();
    if (ts == 0) {
        int r = 0;
#pragma unroll
        for (int s = 0; s < 16; s++) r += part[s][tj];
        Fsorted[nb + r] = fj;
        perm[nb + r] = j;
    }
}

// ---------- Kernel 3: chunked prefix scans (r6-verified 128-thread form) ----------
// r8's 512-thread restructure (+2.3us) and r9's float2 QL interleave (+1.8us)
// both regressed -> r6 form restored: 32-deep independent gather batch,
// separate Q0L/Q1L streams.
__global__ __launch_bounds__(128) void GraphAttentionalLayer_1168231104632_scan(
    const float* __restrict__ hw,
    const float* __restrict__ Fsorted,
    const int* __restrict__ perm,
    float* __restrict__ Q0L, float* __restrict__ Q1L,
    float* __restrict__ C0,  float* __restrict__ C1)
{
    const int t = threadIdx.x;
    const int b = blockIdx.x / NC, c = blockIdx.x % NC;
    const size_t nb = (size_t)b * NN;
    const int m0 = c * CH;

    int   jv[CH];
    float Fv[CH];
#pragma unroll
    for (int mm = 0; mm < CH; mm++) jv[mm] = perm[nb + m0 + mm];
#pragma unroll
    for (int mm = 0; mm < CH; mm++) Fv[mm] = Fsorted[nb + m0 + mm];

    float hv[CH];
#pragma unroll
    for (int mm = 0; mm < CH; mm++)
        hv[mm] = hw[(nb + jv[mm]) * DD + t];

    float a0 = 0.f, a1 = 0.f;
#pragma unroll
    for (int mm = 0; mm < CH; mm++) {
        const int m = m0 + mm;
        Q0L[(nb + m) * DD + t] = a0;
        Q1L[(nb + m) * DD + t] = a1;
        a0 += hv[mm];
        a1 += Fv[mm] * hv[mm];
    }
    C0[((size_t)b * NC + c) * DD + t] = a0;
    C1[((size_t)b * NC + c) * DD + t] = a1;
}

// ---------- Kernel 4 (mid): fix offsets + parallel LDS search (r6-verified) ----------
__global__ __launch_bounds__(256) void GraphAttentionalLayer_1168231104632_mid(
    const float* __restrict__ C0, const float* __restrict__ C1,
    const float* __restrict__ Fsorted, const float* __restrict__ E,
    float* __restrict__ O0, float* __restrict__ O1,
    int* __restrict__ kk,  float* __restrict__ zinv)
{
    __shared__ float fs_s[NN];      // 8 KB
    __shared__ float cf_s[NC];
    __shared__ float of_s[NO];

    const int tid = threadIdx.x;

    if (blockIdx.x < NFIX) {
        const int b = blockIdx.x / NO, c = blockIdx.x % NO;
        const int d = tid & 127;
        const float* C = (tid < 128) ? C0 : C1;
        float*       O = (tid < 128) ? O0 : O1;
        float o = 0.f;
        int c2 = 0;
        for (; c2 + 16 <= c; c2 += 16) {
            float v[16];
#pragma unroll
            for (int q = 0; q < 16; q++)
                v[q] = C[((size_t)b * NC + c2 + q) * DD + d];
#pragma unroll
            for (int q = 0; q < 16; q++) o += v[q];
        }
        for (; c2 < c; c2++)
            o += C[((size_t)b * NC + c2) * DD + d];
        O[((size_t)b * NO + c) * DD + d] = o;
        return;
    }

    const int sb = blockIdx.x - NFIX;
    const int b = sb >> 3;
    const int i0 = (sb & 7) * 256;
    const size_t nb = (size_t)b * NN;

    for (int q = 0; q < NN / 256; q++)
        fs_s[q * 256 + tid] = Fsorted[nb + q * 256 + tid];
    __syncthreads();

    if (tid < NC) {
        float p = 0.f;
        const int m0 = tid * CH;
#pragma unroll
        for (int mm = 0; mm < CH; mm++) p += fs_s[m0 + mm];
        cf_s[tid] = p;
    }
    __syncthreads();
    if (tid < NO) {
        float p = 0.f;
        for (int c2 = 0; c2 < tid; c2++) p += cf_s[c2];
        of_s[tid] = p;
    }
    __syncthreads();

    const int row = (int)nb + i0 + tid;
    const float Ei = E[row];
    const float thr = 1.0f / Ei;
    int lo = 0, hi = NN;
    while (lo < hi) {
        const int mid = (lo + hi) >> 1;
        if (fs_s[mid] < thr) lo = mid + 1; else hi = mid;
    }
    float fpl = 0.f;
    for (int m = (lo >> 5) << 5; m < lo; m++) fpl += fs_s[m];
    const float TF = of_s[NC];
    const float Pk = of_s[lo >> 5] + fpl;
    const float z = Ei * (TF - Pk) + (float)lo;
    kk[row] = lo;
    zinv[row] = 1.0f / z;
}

// ---------- Kernel 5: output, 16 rows per 256-thread block (r6-verified) ----------
__global__ __launch_bounds__(256) void GraphAttentionalLayer_1168231104632_out(
    const float* __restrict__ Q0L, const float* __restrict__ Q1L,
    const float* __restrict__ O0,  const float* __restrict__ O1,
    const int* __restrict__ kk,    const float* __restrict__ zinv,
    const float* __restrict__ E,   float* __restrict__ out)
{
    const int tid = threadIdx.x;
    const int t  = tid & 127;            // d index
    const int rp = tid >> 7;             // row parity 0/1
    const int r0 = blockIdx.x * OG;      // first row of this block
    const int b  = r0 >> 11;             // batch (constant per block)
    const size_t nb = (size_t)b * NN;
    const float* O0b = O0 + (size_t)b * NO * DD;
    const float* O1b = O1 + (size_t)b * NO * DD;

    const float T1  = O1b[(size_t)NC * DD + t];   // batch totals
    const float TQ0 = O0b[(size_t)NC * DD + t];

#pragma unroll
    for (int q = 0; q < OG / 2; q++) {
        const int row = r0 + q * 2 + rp;
        const int k = kk[row];           // uniform across the row's 128 threads
        const float Ev = E[row];
        const float zv = zinv[row];

        float num;
        if (k < NN) {
            const int c = k >> 5;
            const float q0 = Q0L[(nb + k) * DD + t] + O0b[(size_t)c * DD + t];
            const float q1 = Q1L[(nb + k) * DD + t] + O1b[(size_t)c * DD + t];
            num = Ev * (T1 - q1) + q0;
        } else {
            num = TQ0;
        }
        out[(size_t)row * DD + t] = relu(num * zv);
    }
}

extern "C" __attribute__((visibility("default")))
void kernel_launch(void* const* d_in, const int* in_sizes, int n_in,
                   void* d_out, int out_size, void* d_ws, size_t ws_size,
                   hipStream_t stream) {
    const float* h = nullptr; const float* W = nullptr; const float* a = nullptr;
    for (int i = 0; i < n_in; i++) {
        if (in_sizes[i] == BB * NN * DD)      h = (const float*)d_in[i];
        else if (in_sizes[i] == DD * DD)      W = (const float*)d_in[i];
        else if (in_sizes[i] == 2 * DD)       a = (const float*)d_in[i];
    }
    if (!h) h = (const float*)d_in[0];
    if (!W) W = (const float*)d_in[1];
    if (!a) a = (const float*)d_in[2];

    float* out = (float*)d_out;
    float* ws = (float*)d_ws;

    float* hw   = ws;                              // 2,097,152
    float* E    = hw + (size_t)BB * NN * DD;       // 16,384
    float* F    = E + BB * NN;                     // 16,384
    float* Fs   = F + BB * NN;                     // 16,384
    float* zinv = Fs + BB * NN;                    // 16,384
    int*   perm = (int*)(zinv + BB * NN);          // 16,384
    int*   kk   = perm + BB * NN;                  // 16,384
    float* Q0L  = (float*)(kk + BB * NN);          // 2,097,152
    float* Q1L  = Q0L + (size_t)BB * NN * DD;      // 2,097,152
    float* C0   = Q1L + (size_t)BB * NN * DD;      // 65,536
    float* C1   = C0 + BB * NC * DD;               // 65,536
    float* O0   = C1 + BB * NC * DD;               // 66,560
    float* O1   = O0 + BB * NO * DD;               // 66,560
    const size_t need = (size_t)((O1 + BB * NO * DD) - ws) * sizeof(float); // ~26.3 MB

    if (ws_size < need || d_ws == nullptr) {
        hipMemsetAsync(d_out, 0x42, (size_t)out_size * sizeof(float), stream);
        return;
    }

    GraphAttentionalLayer_1168231104632_kernel<<<BB * (NN / TI), 256, 0, stream>>>(h, W, a, hw, E, F);
    GraphAttentionalLayer_1168231104632_rank<<<BB * RB, 256, 0, stream>>>(F, Fs, perm);
    GraphAttentionalLayer_1168231104632_scan<<<BB * NC, 128, 0, stream>>>(hw, Fs, perm, Q0L, Q1L, C0, C1);
    GraphAttentionalLayer_1168231104632_mid<<<NFIX + BB * 8, 256, 0, stream>>>(C0, C1, Fs, E, O0, O1, kk, zinv);
    GraphAttentionalLayer_1168231104632_out<<<(BB * NN) / OG, 256, 0, stream>>>(Q0L, Q1L, O0, O1, kk, zinv, E, out);
}